// Round 1
// baseline (1310.487 us; speedup 1.0000x reference)
//
#include <hip/hip_runtime.h>
#include <cstdint>
#include <cstddef>

#define F_IN 128
#define HID 64
#define DMID 128
#define NOUT 40
#define BN_EPS 1e-5f

static inline int ceil_div_l(long a, long b){ return (int)((a + b - 1) / b); }

// ---------- degree / norm ----------
__global__ void k_count(const int* __restrict__ dst, int* __restrict__ cnt, int E){
  int e = blockIdx.x * blockDim.x + threadIdx.x;
  if (e < E) atomicAdd(&cnt[dst[e]], 1);
}

__global__ void k_dinv(const int* __restrict__ cnt, float* __restrict__ dinv, int n){
  int i = blockIdx.x * blockDim.x + threadIdx.x;
  if (i < n) dinv[i] = rsqrtf(1.0f + (float)cnt[i]);   // +1 = self loop
}

// ---------- CSR build: reduce -> top scan -> local scan -> place ----------
__global__ void k_block_reduce(const int* __restrict__ cnt, int* __restrict__ bsum, int n){
  __shared__ int s[256];
  int i = blockIdx.x * 256 + threadIdx.x;
  s[threadIdx.x] = (i < n) ? cnt[i] : 0;
  __syncthreads();
  for (int o = 128; o > 0; o >>= 1){
    if (threadIdx.x < o) s[threadIdx.x] += s[threadIdx.x + o];
    __syncthreads();
  }
  if (threadIdx.x == 0) bsum[blockIdx.x] = s[0];
}

__global__ void k_top_scan(const int* __restrict__ bsum, int* __restrict__ boff, int nb){
  if (threadIdx.x == 0 && blockIdx.x == 0){
    int acc = 0;
    for (int b = 0; b < nb; b++){ boff[b] = acc; acc += bsum[b]; }
  }
}

__global__ void k_local_scan(const int* __restrict__ cnt, const int* __restrict__ boff,
                             int* __restrict__ rowstart, int n){
  __shared__ int s[256];
  int i = blockIdx.x * 256 + threadIdx.x;
  int v = (i < n) ? cnt[i] : 0;
  s[threadIdx.x] = v;
  __syncthreads();
  for (int o = 1; o < 256; o <<= 1){
    int t = (threadIdx.x >= o) ? s[threadIdx.x - o] : 0;
    __syncthreads();
    s[threadIdx.x] += t;
    __syncthreads();
  }
  if (i < n) rowstart[i] = boff[blockIdx.x] + s[threadIdx.x] - v;  // exclusive scan
}

__global__ void k_place(const int* __restrict__ src, const int* __restrict__ dst,
                        const int* __restrict__ rowstart, int* __restrict__ fill,
                        int* __restrict__ csr, int E){
  int e = blockIdx.x * blockDim.x + threadIdx.x;
  if (e < E){
    int d = dst[e];
    int p = rowstart[d] + atomicAdd(&fill[d], 1);
    csr[p] = src[e];
  }
}

// ---------- GEMMs (fp32 vector ALU; W staged in LDS) ----------
// A[n][c] : c<64 -> x0 @ W_init[0][:,c] ; c>=64 -> x1 @ W_init[1][:,c-64]
__launch_bounds__(256)
__global__ void k_gemm_init(const float* __restrict__ x0, const float* __restrict__ x1,
                            const float* __restrict__ W, float* __restrict__ A, int n){
  __shared__ float Wl[128 * 128];          // 64 KB: Wl[k][c]
  for (int i = threadIdx.x; i < 128 * 128; i += 256){
    int k = i >> 7, c = i & 127;
    Wl[i] = W[((c >> 6) * 128 + k) * 64 + (c & 63)];
  }
  __syncthreads();
  int c    = threadIdx.x & 127;
  int half = threadIdx.x >> 7;
  const float* xb = (c < 64) ? x0 : x1;    // wave-uniform (lanes 0..63 all c<64 etc.)
  for (int r = blockIdx.x * 2 + half; r < n; r += gridDim.x * 2){
    const float* xr = xb + (size_t)r * 128;
    float acc = 0.f;
    #pragma unroll 8
    for (int k = 0; k < 128; k++) acc += xr[k] * Wl[k * 128 + c];
    A[(size_t)r * 128 + c] = acc;
  }
}

__launch_bounds__(256)
__global__ void k_gemm128(const float* __restrict__ X, const float* __restrict__ W,
                          float* __restrict__ Y, int n){
  __shared__ float Wl[128 * 128];          // W[k][j] row-major, as given
  for (int i = threadIdx.x; i < 128 * 128; i += 256) Wl[i] = W[i];
  __syncthreads();
  int c = threadIdx.x & 127, half = threadIdx.x >> 7;
  for (int r = blockIdx.x * 2 + half; r < n; r += gridDim.x * 2){
    const float* xr = X + (size_t)r * 128;
    float acc = 0.f;
    #pragma unroll 8
    for (int k = 0; k < 128; k++) acc += xr[k] * Wl[k * 128 + c];
    Y[(size_t)r * 128 + c] = acc;
  }
}

__launch_bounds__(256)
__global__ void k_gemm_out(const float* __restrict__ X, const float* __restrict__ W,
                           float* __restrict__ Y, int n){
  __shared__ float Wl[128 * NOUT];         // 20 KB
  for (int i = threadIdx.x; i < 128 * NOUT; i += 256) Wl[i] = W[i];
  __syncthreads();
  int c  = threadIdx.x % NOUT;
  int rl = threadIdx.x / NOUT;             // 0..6 ; rl==6 (tid 240..255) idle
  if (rl >= 6) return;
  for (int r = blockIdx.x * 6 + rl; r < n; r += gridDim.x * 6){
    const float* xr = X + (size_t)r * 128;
    float acc = 0.f;
    #pragma unroll 8
    for (int k = 0; k < 128; k++) acc += xr[k] * Wl[k * NOUT + c];
    Y[(size_t)r * NOUT + c] = acc;
  }
}

// ---------- aggregation (CSR gather): out[n] = di*(sum_s h[s]*dinv[s]) + di^2*h[n] ----------
__global__ void k_agg128(const float* __restrict__ H, float* __restrict__ Y,
                         const int* __restrict__ rowstart, const int* __restrict__ cnt,
                         const int* __restrict__ csr, const float* __restrict__ dinv, int n){
  int t = blockIdx.x * blockDim.x + threadIdx.x;
  int node = t >> 5, c4 = t & 31;
  if (node >= n) return;
  const float4* Hv = (const float4*)H;
  float di = dinv[node];
  float4 acc = Hv[(size_t)node * 32 + c4];
  acc.x *= di; acc.y *= di; acc.z *= di; acc.w *= di;   // self term (×di again at end)
  int beg = rowstart[node], num = cnt[node];
  for (int i = 0; i < num; i++){
    int s = csr[beg + i];
    float w = dinv[s];
    float4 v = Hv[(size_t)s * 32 + c4];
    acc.x += v.x * w; acc.y += v.y * w; acc.z += v.z * w; acc.w += v.w * w;
  }
  acc.x *= di; acc.y *= di; acc.z *= di; acc.w *= di;
  ((float4*)Y)[(size_t)node * 32 + c4] = acc;
}

__global__ void k_agg40(const float* __restrict__ H, const float* __restrict__ bout,
                        float* __restrict__ Y, const int* __restrict__ rowstart,
                        const int* __restrict__ cnt, const int* __restrict__ csr,
                        const float* __restrict__ dinv, int n){
  int t = blockIdx.x * blockDim.x + threadIdx.x;
  int node = t >> 4, c4 = t & 15;
  if (node >= n || c4 >= 10) return;
  float di = dinv[node];
  const float* hr = H + (size_t)node * NOUT + c4 * 4;
  float4 acc = *(const float4*)hr;
  acc.x *= di; acc.y *= di; acc.z *= di; acc.w *= di;
  int beg = rowstart[node], num = cnt[node];
  for (int i = 0; i < num; i++){
    int s = csr[beg + i];
    float w = dinv[s];
    float4 v = *(const float4*)(H + (size_t)s * NOUT + c4 * 4);
    acc.x += v.x * w; acc.y += v.y * w; acc.z += v.z * w; acc.w += v.w * w;
  }
  float4 bb = *(const float4*)(bout + c4 * 4);
  acc.x = acc.x * di + bb.x; acc.y = acc.y * di + bb.y;
  acc.z = acc.z * di + bb.z; acc.w = acc.w * di + bb.w;
  *(float4*)(Y + (size_t)node * NOUT + c4 * 4) = acc;
}

// ---------- BatchNorm (batch stats) ----------
__global__ void k_bn_stats(const float* __restrict__ X, float* __restrict__ sum,
                           float* __restrict__ sq, int n){
  int c = threadIdx.x & 127, half = threadIdx.x >> 7;
  float s = 0.f, q = 0.f;
  for (int r = blockIdx.x * 2 + half; r < n; r += gridDim.x * 2){
    float v = X[(size_t)r * 128 + c];
    s += v; q += v * v;
  }
  __shared__ float ls[256], lq[256];
  ls[threadIdx.x] = s; lq[threadIdx.x] = q;
  __syncthreads();
  if (threadIdx.x < 128){
    s = ls[threadIdx.x] + ls[threadIdx.x + 128];
    q = lq[threadIdx.x] + lq[threadIdx.x + 128];
    atomicAdd(&sum[c], s); atomicAdd(&sq[c], q);
  }
}

__global__ void k_bn_fin(const float* __restrict__ sum, const float* __restrict__ sq,
                         const float* __restrict__ g, const float* __restrict__ beta,
                         float* __restrict__ scale, float* __restrict__ shift, int n){
  int c = threadIdx.x;
  if (c < 128){
    float invn = 1.0f / (float)n;
    float mu  = sum[c] * invn;
    float var = sq[c] * invn - mu * mu;
    var = var > 0.f ? var : 0.f;
    float sc = g[c] * rsqrtf(var + BN_EPS);
    scale[c] = sc;
    shift[c] = beta[c] - mu * sc;
  }
}

__global__ void k_bn_apply(float* __restrict__ X, const float* __restrict__ scale,
                           const float* __restrict__ shift, long total){
  long i = (long)blockIdx.x * blockDim.x + threadIdx.x;
  if (i < total){
    int c = (int)(i & 127);
    float v = X[i] * scale[c] + shift[c];
    X[i] = v > 0.f ? v : 0.f;
  }
}

// ---------- launch ----------
extern "C" void kernel_launch(void* const* d_in, const int* in_sizes, int n_in,
                              void* d_out, int out_size, void* d_ws, size_t ws_size,
                              hipStream_t stream) {
  const float* x0        = (const float*)d_in[0];
  const float* x1        = (const float*)d_in[1];
  const int*   ei        = (const int*)  d_in[2];
  const float* W_init    = (const float*)d_in[3];
  // d_in[4] b_init: cancels exactly in BN (constant column shift) -> unused
  const float* g_init    = (const float*)d_in[5];
  const float* beta_init = (const float*)d_in[6];
  const float* W_mid     = (const float*)d_in[7];
  // d_in[8] b_mid: cancels in BN -> unused
  const float* g_mid     = (const float*)d_in[9];
  const float* beta_mid  = (const float*)d_in[10];
  const float* W_out     = (const float*)d_in[11];
  const float* b_out     = (const float*)d_in[12];

  int N = in_sizes[0] / F_IN;
  int E = in_sizes[2] / 2;
  const int* esrc = ei;
  const int* edst = ei + E;

  char* w = (char*)d_ws;
  size_t off = 0;
  auto take = [&](size_t bytes) -> char* {
    char* p = w + off;
    off = (off + bytes + 255) & ~(size_t)255;
    return p;
  };
  float* dinv     = (float*)take((size_t)N * 4);
  int*   cnt      = (int*)  take((size_t)N * 4);
  int*   fill     = (int*)  take((size_t)N * 4);
  int*   rowstart = (int*)  take((size_t)N * 4);
  int NB = ceil_div_l(N, 256);
  int*   bsum     = (int*)  take((size_t)NB * 4);
  int*   boff     = (int*)  take((size_t)NB * 4);
  float* stats    = (float*)take(1024 * 4);
  int*   csr      = (int*)  take((size_t)E * 4);
  float* A        = (float*)take((size_t)N * 128 * 4);
  float* B        = (float*)take((size_t)N * 128 * 4);
  (void)ws_size; (void)n_in; (void)out_size;

  float* sum1 = stats,       *sq1 = stats + 128, *scale1 = stats + 256, *shift1 = stats + 384;
  float* sum2 = stats + 512, *sq2 = stats + 640, *scale2 = stats + 768, *shift2 = stats + 896;

  hipMemsetAsync(cnt,   0, (size_t)N * 4, stream);
  hipMemsetAsync(fill,  0, (size_t)N * 4, stream);
  hipMemsetAsync(stats, 0, 1024 * 4, stream);

  // norm + CSR
  k_count<<<ceil_div_l(E,256),256,0,stream>>>(edst, cnt, E);
  k_dinv <<<ceil_div_l(N,256),256,0,stream>>>(cnt, dinv, N);
  k_block_reduce<<<NB,256,0,stream>>>(cnt, bsum, N);
  k_top_scan   <<<1,64,0,stream>>>(bsum, boff, NB);
  k_local_scan <<<NB,256,0,stream>>>(cnt, boff, rowstart, N);
  k_place<<<ceil_div_l(E,256),256,0,stream>>>(esrc, edst, rowstart, fill, csr, E);

  // layer 1 (both branches fused, concat layout)
  k_gemm_init<<<2048,256,0,stream>>>(x0, x1, W_init, A, N);
  k_agg128<<<ceil_div_l((long)N*32,256),256,0,stream>>>(A, B, rowstart, cnt, csr, dinv, N);
  k_bn_stats<<<512,256,0,stream>>>(B, sum1, sq1, N);
  k_bn_fin<<<1,128,0,stream>>>(sum1, sq1, g_init, beta_init, scale1, shift1, N);
  k_bn_apply<<<ceil_div_l((long)N*128,256),256,0,stream>>>(B, scale1, shift1, (long)N*128);

  // layer 2
  k_gemm128<<<2048,256,0,stream>>>(B, W_mid, A, N);
  k_agg128<<<ceil_div_l((long)N*32,256),256,0,stream>>>(A, B, rowstart, cnt, csr, dinv, N);
  k_bn_stats<<<512,256,0,stream>>>(B, sum2, sq2, N);
  k_bn_fin<<<1,128,0,stream>>>(sum2, sq2, g_mid, beta_mid, scale2, shift2, N);
  k_bn_apply<<<ceil_div_l((long)N*128,256),256,0,stream>>>(B, scale2, shift2, (long)N*128);

  // layer 3 (no BN; b_out applied in aggregation)
  k_gemm_out<<<2048,256,0,stream>>>(B, W_out, A, N);
  k_agg40<<<ceil_div_l((long)N*16,256),256,0,stream>>>(A, b_out, (float*)d_out,
                                                       rowstart, cnt, csr, dinv, N);
}

// Round 2
// 892.440 us; speedup vs baseline: 1.4684x; 1.4684x over previous
//
#include <hip/hip_runtime.h>
#include <cstdint>
#include <cstddef>

#define F_IN 128
#define NOUT 40
#define BN_EPS 1e-5f

static inline int ceil_div_l(long a, long b){ return (int)((a + b - 1) / b); }

__device__ __forceinline__ float4 f4zero(){ return make_float4(0.f,0.f,0.f,0.f); }
__device__ __forceinline__ float4 f4fma(float a, float4 b, float4 c){
  c.x = fmaf(a, b.x, c.x); c.y = fmaf(a, b.y, c.y);
  c.z = fmaf(a, b.z, c.z); c.w = fmaf(a, b.w, c.w); return c;
}

// ---------- degree / norm ----------
__global__ void k_count(const int* __restrict__ dst, int* __restrict__ cnt, int E){
  int e = blockIdx.x * blockDim.x + threadIdx.x;
  if (e < E) atomicAdd(&cnt[dst[e]], 1);
}

__global__ void k_dinv(const int* __restrict__ cnt, float* __restrict__ dinv, int n){
  int i = blockIdx.x * blockDim.x + threadIdx.x;
  if (i < n) dinv[i] = rsqrtf(1.0f + (float)cnt[i]);   // +1 = self loop
}

// ---------- CSR build ----------
__global__ void k_block_reduce(const int* __restrict__ cnt, int* __restrict__ bsum, int n){
  __shared__ int s[256];
  int i = blockIdx.x * 256 + threadIdx.x;
  s[threadIdx.x] = (i < n) ? cnt[i] : 0;
  __syncthreads();
  for (int o = 128; o > 0; o >>= 1){
    if (threadIdx.x < o) s[threadIdx.x] += s[threadIdx.x + o];
    __syncthreads();
  }
  if (threadIdx.x == 0) bsum[blockIdx.x] = s[0];
}

__global__ void k_top_scan(const int* __restrict__ bsum, int* __restrict__ boff, int nb){
  if (threadIdx.x == 0 && blockIdx.x == 0){
    int acc = 0;
    for (int b = 0; b < nb; b++){ boff[b] = acc; acc += bsum[b]; }
  }
}

__global__ void k_local_scan(const int* __restrict__ cnt, const int* __restrict__ boff,
                             int* __restrict__ rowstart, int n){
  __shared__ int s[256];
  int i = blockIdx.x * 256 + threadIdx.x;
  int v = (i < n) ? cnt[i] : 0;
  s[threadIdx.x] = v;
  __syncthreads();
  for (int o = 1; o < 256; o <<= 1){
    int t = (threadIdx.x >= o) ? s[threadIdx.x - o] : 0;
    __syncthreads();
    s[threadIdx.x] += t;
    __syncthreads();
  }
  if (i < n) rowstart[i] = boff[blockIdx.x] + s[threadIdx.x] - v;
}

__global__ void k_place(const int* __restrict__ src, const int* __restrict__ dst,
                        const int* __restrict__ rowstart, int* __restrict__ fill,
                        int* __restrict__ csr, int E){
  int e = blockIdx.x * blockDim.x + threadIdx.x;
  if (e < E){
    int d = dst[e];
    int p = rowstart[d] + atomicAdd(&fill[d], 1);
    csr[p] = src[e];
  }
}

// ---------- register-tiled fp32 GEMM: Y[:, col_off:col_off+wcols] = relu(bn(X)) @ W ----------
// Tile: 128 rows x COLS cols per block iteration. W:[128][wcols] row-major.
// scale/shift == nullptr -> raw X. Store only cols < wcols.
template<int COLS>
__launch_bounds__(256, 1)
__global__ void k_gemm(const float* __restrict__ X, const float* __restrict__ W, int wcols,
                       const float* __restrict__ scale, const float* __restrict__ shift,
                       float* __restrict__ Y, int ldY, int col_off, int n, int ntiles){
  constexpr int CG  = COLS / 8;     // col groups (threads in col dim): 16 or 8
  constexpr int RG  = 256 / CG;     // row groups: 16 or 32
  constexpr int RPT = 128 / RG;     // rows per thread: 8 or 4
  constexpr int CF4 = COLS / 4;     // float4s per W row
  constexpr int XS  = 132;          // padded X row stride (floats), 16B-aligned

  extern __shared__ float lds[];
  float* Wl = lds;                  // [128][COLS]
  float* Xl = lds + 128 * COLS;     // [128][132]

  const int tid = threadIdx.x;
  const int tc = tid % CG, tr = tid / CG;

  // stage W once per block (zero-pad cols >= wcols)
  const int wf4 = wcols >> 2;
  for (int idx = tid; idx < 128 * CF4; idx += 256){
    int k = idx / CF4, cw = idx % CF4;
    float4 v = f4zero();
    if (cw < wf4) v = *(const float4*)(W + (size_t)k * wcols + cw * 4);
    *(float4*)(Wl + k * COLS + cw * 4) = v;
  }

  for (int t = blockIdx.x; t < ntiles; t += gridDim.x){
    const int r0 = t * 128;
    __syncthreads();   // protect Xl from previous iteration's readers
    // stage X tile (optionally fused BN+ReLU over feature columns)
    for (int idx = tid; idx < 128 * 32; idx += 256){
      int row = idx >> 5, k4 = idx & 31;
      int gr = r0 + row;
      float4 v = f4zero();
      if (gr < n){
        v = *(const float4*)(X + (size_t)gr * 128 + k4 * 4);
        if (scale){
          float4 sc = *(const float4*)(scale + k4 * 4);
          float4 sh = *(const float4*)(shift + k4 * 4);
          v.x = fmaxf(fmaf(v.x, sc.x, sh.x), 0.f);
          v.y = fmaxf(fmaf(v.y, sc.y, sh.y), 0.f);
          v.z = fmaxf(fmaf(v.z, sc.z, sh.z), 0.f);
          v.w = fmaxf(fmaf(v.w, sc.w, sh.w), 0.f);
        }
      }
      *(float4*)(Xl + row * XS + k4 * 4) = v;
    }
    __syncthreads();

    float4 acc[RPT][2];
    #pragma unroll
    for (int i = 0; i < RPT; i++){ acc[i][0] = f4zero(); acc[i][1] = f4zero(); }

    for (int k4 = 0; k4 < 32; k4++){
      float4 xv[RPT];
      #pragma unroll
      for (int i = 0; i < RPT; i++)
        xv[i] = *(const float4*)(Xl + (tr + RG * i) * XS + k4 * 4);
      float4 wv[4][2];
      #pragma unroll
      for (int kk = 0; kk < 4; kk++){
        wv[kk][0] = *(const float4*)(Wl + (k4 * 4 + kk) * COLS + (tc         ) * 4);
        wv[kk][1] = *(const float4*)(Wl + (k4 * 4 + kk) * COLS + (tc + CG    ) * 4);
      }
      #pragma unroll
      for (int i = 0; i < RPT; i++){
        acc[i][0] = f4fma(xv[i].x, wv[0][0], acc[i][0]);
        acc[i][1] = f4fma(xv[i].x, wv[0][1], acc[i][1]);
        acc[i][0] = f4fma(xv[i].y, wv[1][0], acc[i][0]);
        acc[i][1] = f4fma(xv[i].y, wv[1][1], acc[i][1]);
        acc[i][0] = f4fma(xv[i].z, wv[2][0], acc[i][0]);
        acc[i][1] = f4fma(xv[i].z, wv[2][1], acc[i][1]);
        acc[i][0] = f4fma(xv[i].w, wv[3][0], acc[i][0]);
        acc[i][1] = f4fma(xv[i].w, wv[3][1], acc[i][1]);
      }
    }

    #pragma unroll
    for (int i = 0; i < RPT; i++){
      int row = r0 + tr + RG * i;
      if (row < n){
        #pragma unroll
        for (int jq = 0; jq < 2; jq++){
          int cq = (tc + CG * jq) * 4;
          if (cq < wcols)
            *(float4*)(Y + (size_t)row * ldY + col_off + cq) = acc[i][jq];
        }
      }
    }
  }
}

// ---------- aggregation (CSR gather): out[n] = di*(sum_s h[s]*dinv[s]) + di^2*h[n] ----------
__global__ void k_agg128(const float* __restrict__ H, float* __restrict__ Y,
                         const int* __restrict__ rowstart, const int* __restrict__ cnt,
                         const int* __restrict__ csr, const float* __restrict__ dinv, int n){
  int t = blockIdx.x * blockDim.x + threadIdx.x;
  int node = t >> 5, c4 = t & 31;
  if (node >= n) return;
  const float4* Hv = (const float4*)H;
  float di = dinv[node];
  float4 acc = Hv[(size_t)node * 32 + c4];
  acc.x *= di; acc.y *= di; acc.z *= di; acc.w *= di;
  int beg = rowstart[node], num = cnt[node];
  for (int i = 0; i < num; i++){
    int s = csr[beg + i];
    float w = dinv[s];
    float4 v = Hv[(size_t)s * 32 + c4];
    acc.x = fmaf(v.x, w, acc.x); acc.y = fmaf(v.y, w, acc.y);
    acc.z = fmaf(v.z, w, acc.z); acc.w = fmaf(v.w, w, acc.w);
  }
  acc.x *= di; acc.y *= di; acc.z *= di; acc.w *= di;
  ((float4*)Y)[(size_t)node * 32 + c4] = acc;
}

__global__ void k_agg40(const float* __restrict__ H, const float* __restrict__ bout,
                        float* __restrict__ Y, const int* __restrict__ rowstart,
                        const int* __restrict__ cnt, const int* __restrict__ csr,
                        const float* __restrict__ dinv, int n){
  int t = blockIdx.x * blockDim.x + threadIdx.x;
  int node = t >> 4, c4 = t & 15;
  if (node >= n || c4 >= 10) return;
  float di = dinv[node];
  float4 acc = *(const float4*)(H + (size_t)node * NOUT + c4 * 4);
  acc.x *= di; acc.y *= di; acc.z *= di; acc.w *= di;
  int beg = rowstart[node], num = cnt[node];
  for (int i = 0; i < num; i++){
    int s = csr[beg + i];
    float w = dinv[s];
    const float* hp = H + (size_t)s * NOUT + c4 * 4;
    float4 v = *(const float4*)hp;
    acc.x = fmaf(v.x, w, acc.x); acc.y = fmaf(v.y, w, acc.y);
    acc.z = fmaf(v.z, w, acc.z); acc.w = fmaf(v.w, w, acc.w);
  }
  float4 bb = *(const float4*)(bout + c4 * 4);
  acc.x = fmaf(acc.x, di, bb.x); acc.y = fmaf(acc.y, di, bb.y);
  acc.z = fmaf(acc.z, di, bb.z); acc.w = fmaf(acc.w, di, bb.w);
  *(float4*)(Y + (size_t)node * NOUT + c4 * 4) = acc;
}

// ---------- BatchNorm stats ----------
__global__ void k_bn_stats(const float* __restrict__ X, float* __restrict__ sum,
                           float* __restrict__ sq, int n){
  int c = threadIdx.x & 127, half = threadIdx.x >> 7;
  float s = 0.f, q = 0.f;
  for (int r = blockIdx.x * 2 + half; r < n; r += gridDim.x * 2){
    float v = X[(size_t)r * 128 + c];
    s += v; q = fmaf(v, v, q);
  }
  __shared__ float ls[256], lq[256];
  ls[threadIdx.x] = s; lq[threadIdx.x] = q;
  __syncthreads();
  if (threadIdx.x < 128){
    s = ls[threadIdx.x] + ls[threadIdx.x + 128];
    q = lq[threadIdx.x] + lq[threadIdx.x + 128];
    atomicAdd(&sum[c], s); atomicAdd(&sq[c], q);
  }
}

__global__ void k_bn_fin(const float* __restrict__ sum, const float* __restrict__ sq,
                         const float* __restrict__ g, const float* __restrict__ beta,
                         float* __restrict__ scale, float* __restrict__ shift, int n){
  int c = threadIdx.x;
  if (c < 128){
    float invn = 1.0f / (float)n;
    float mu  = sum[c] * invn;
    float var = sq[c] * invn - mu * mu;
    var = var > 0.f ? var : 0.f;
    float sc = g[c] * rsqrtf(var + BN_EPS);
    scale[c] = sc;
    shift[c] = beta[c] - mu * sc;
  }
}

// ---------- launch ----------
extern "C" void kernel_launch(void* const* d_in, const int* in_sizes, int n_in,
                              void* d_out, int out_size, void* d_ws, size_t ws_size,
                              hipStream_t stream) {
  const float* x0        = (const float*)d_in[0];
  const float* x1        = (const float*)d_in[1];
  const int*   ei        = (const int*)  d_in[2];
  const float* W_init    = (const float*)d_in[3];
  const float* g_init    = (const float*)d_in[5];
  const float* beta_init = (const float*)d_in[6];
  const float* W_mid     = (const float*)d_in[7];
  const float* g_mid     = (const float*)d_in[9];
  const float* beta_mid  = (const float*)d_in[10];
  const float* W_out     = (const float*)d_in[11];
  const float* b_out     = (const float*)d_in[12];

  int N = in_sizes[0] / F_IN;
  int E = in_sizes[2] / 2;
  const int* esrc = ei;
  const int* edst = ei + E;

  char* w = (char*)d_ws;
  size_t off = 0;
  auto take = [&](size_t bytes) -> char* {
    char* p = w + off;
    off = (off + bytes + 255) & ~(size_t)255;
    return p;
  };
  float* dinv     = (float*)take((size_t)N * 4);
  int*   cnt      = (int*)  take((size_t)N * 4);
  int*   fill     = (int*)  take((size_t)N * 4);
  int*   rowstart = (int*)  take((size_t)N * 4);
  int NB = ceil_div_l(N, 256);
  int*   bsum     = (int*)  take((size_t)NB * 4);
  int*   boff     = (int*)  take((size_t)NB * 4);
  float* stats    = (float*)take(1024 * 4);
  int*   csr      = (int*)  take((size_t)E * 4);
  float* A        = (float*)take((size_t)N * 128 * 4);
  float* B        = (float*)take((size_t)N * 128 * 4);
  (void)ws_size; (void)n_in; (void)out_size;

  float* sum1 = stats,       *sq1 = stats + 128, *scale1 = stats + 256, *shift1 = stats + 384;
  float* sum2 = stats + 512, *sq2 = stats + 640, *scale2 = stats + 768, *shift2 = stats + 896;

  hipMemsetAsync(cnt,   0, (size_t)N * 4, stream);
  hipMemsetAsync(fill,  0, (size_t)N * 4, stream);
  hipMemsetAsync(stats, 0, 1024 * 4, stream);

  // norm + CSR
  k_count<<<ceil_div_l(E,256),256,0,stream>>>(edst, cnt, E);
  k_dinv <<<ceil_div_l(N,256),256,0,stream>>>(cnt, dinv, N);
  k_block_reduce<<<NB,256,0,stream>>>(cnt, bsum, N);
  k_top_scan   <<<1,64,0,stream>>>(bsum, boff, NB);
  k_local_scan <<<NB,256,0,stream>>>(cnt, boff, rowstart, N);
  k_place<<<ceil_div_l(E,256),256,0,stream>>>(esrc, edst, rowstart, fill, csr, E);

  const int ntiles = ceil_div_l(N, 128);
  const size_t lds128 = (size_t)(128 * 128 + 128 * 132) * 4;  // 131584 B
  const size_t lds64  = (size_t)(128 *  64 + 128 * 132) * 4;  // 100352 B

  // layer 1: two branch GEMMs into concat layout (no BN on input)
  k_gemm<64><<<256,256,lds64,stream>>>(x0, W_init,            64, nullptr, nullptr, A, 128,  0, N, ntiles);
  k_gemm<64><<<256,256,lds64,stream>>>(x1, W_init + 128*64,   64, nullptr, nullptr, A, 128, 64, N, ntiles);
  k_agg128<<<ceil_div_l((long)N*32,256),256,0,stream>>>(A, B, rowstart, cnt, csr, dinv, N);
  k_bn_stats<<<512,256,0,stream>>>(B, sum1, sq1, N);
  k_bn_fin<<<1,128,0,stream>>>(sum1, sq1, g_init, beta_init, scale1, shift1, N);

  // layer 2: BN1+ReLU fused into X staging
  k_gemm<128><<<256,256,lds128,stream>>>(B, W_mid, 128, scale1, shift1, A, 128, 0, N, ntiles);
  k_agg128<<<ceil_div_l((long)N*32,256),256,0,stream>>>(A, B, rowstart, cnt, csr, dinv, N);
  k_bn_stats<<<512,256,0,stream>>>(B, sum2, sq2, N);
  k_bn_fin<<<1,128,0,stream>>>(sum2, sq2, g_mid, beta_mid, scale2, shift2, N);

  // layer 3: BN2+ReLU fused; compute 64 cols (24 zero-padded), store 40
  k_gemm<64><<<256,256,lds64,stream>>>(B, W_out, 40, scale2, shift2, A, 40, 0, N, ntiles);
  k_agg40<<<ceil_div_l((long)N*16,256),256,0,stream>>>(A, b_out, (float*)d_out,
                                                       rowstart, cnt, csr, dinv, N);
}

// Round 3
// 710.938 us; speedup vs baseline: 1.8433x; 1.2553x over previous
//
#include <hip/hip_runtime.h>
#include <cstdint>
#include <cstddef>

#define F_IN 128
#define NOUT 40
#define BN_EPS 1e-5f

typedef unsigned short u16;
typedef unsigned int u32;

static inline int ceil_div_l(long a, long b){ return (int)((a + b - 1) / b); }

__device__ __forceinline__ float4 f4zero(){ return make_float4(0.f,0.f,0.f,0.f); }
__device__ __forceinline__ float4 f4fma(float a, float4 b, float4 c){
  c.x = fmaf(a, b.x, c.x); c.y = fmaf(a, b.y, c.y);
  c.z = fmaf(a, b.z, c.z); c.w = fmaf(a, b.w, c.w); return c;
}
__device__ __forceinline__ float b2f(u16 h){
  union { u32 u; float f; } v; v.u = ((u32)h) << 16; return v.f;
}
__device__ __forceinline__ u16 f2b(float x){
  union { float f; u32 u; } v; v.f = x;
  u32 r = v.u + 0x7FFFu + ((v.u >> 16) & 1u);
  return (u16)(r >> 16);
}

// ---------- degree / norm ----------
__global__ void k_count(const int* __restrict__ dst, int* __restrict__ cnt, int E){
  int e = blockIdx.x * blockDim.x + threadIdx.x;
  if (e < E) atomicAdd(&cnt[dst[e]], 1);
}

__global__ void k_dinv(const int* __restrict__ cnt, float* __restrict__ dinv, int n){
  int i = blockIdx.x * blockDim.x + threadIdx.x;
  if (i < n) dinv[i] = rsqrtf(1.0f + (float)cnt[i]);   // +1 = self loop
}

// ---------- CSR build ----------
__global__ void k_block_reduce(const int* __restrict__ cnt, int* __restrict__ bsum, int n){
  __shared__ int s[256];
  int i = blockIdx.x * 256 + threadIdx.x;
  s[threadIdx.x] = (i < n) ? cnt[i] : 0;
  __syncthreads();
  for (int o = 128; o > 0; o >>= 1){
    if (threadIdx.x < o) s[threadIdx.x] += s[threadIdx.x + o];
    __syncthreads();
  }
  if (threadIdx.x == 0) bsum[blockIdx.x] = s[0];
}

__global__ void k_top_scan(const int* __restrict__ bsum, int* __restrict__ boff, int nb){
  if (threadIdx.x == 0 && blockIdx.x == 0){
    int acc = 0;
    for (int b = 0; b < nb; b++){ boff[b] = acc; acc += bsum[b]; }
  }
}

__global__ void k_local_scan(const int* __restrict__ cnt, const int* __restrict__ boff,
                             int* __restrict__ rowstart, int n){
  __shared__ int s[256];
  int i = blockIdx.x * 256 + threadIdx.x;
  int v = (i < n) ? cnt[i] : 0;
  s[threadIdx.x] = v;
  __syncthreads();
  for (int o = 1; o < 256; o <<= 1){
    int t = (threadIdx.x >= o) ? s[threadIdx.x - o] : 0;
    __syncthreads();
    s[threadIdx.x] += t;
    __syncthreads();
  }
  if (i < n) rowstart[i] = boff[blockIdx.x] + s[threadIdx.x] - v;
}

__global__ void k_place(const int* __restrict__ src, const int* __restrict__ dst,
                        const int* __restrict__ rowstart, int* __restrict__ fill,
                        int* __restrict__ csr, int E){
  int e = blockIdx.x * blockDim.x + threadIdx.x;
  if (e < E){
    int d = dst[e];
    int p = rowstart[d] + atomicAdd(&fill[d], 1);
    csr[p] = src[e];
  }
}

// ---------- register-tiled GEMM, 128-row x 64-col tile, bf16 out ----------
// X: fp32 [n][128] (XBF=false) or bf16 [n][128] (XBF=true). W: fp32 [128][ldW].
// BN=true: apply x*scale+shift, relu during staging (fp32 math).
// LDS: W 32KB fp32 + X-tile 34.8KB bf16 = 67.6KB -> 2 blocks/CU.
template<bool XBF, bool BN>
__launch_bounds__(256, 2)
__global__ void k_gemm64(const void* __restrict__ Xv, const float* __restrict__ W,
                         int ldW, int wcols,
                         const float* __restrict__ scale, const float* __restrict__ shift,
                         u16* __restrict__ Y, int ldY, int col_off, int n, int ntiles){
  __shared__ float Wl[128 * 64];      // [k][c]
  __shared__ u16   Xl[128 * 136];     // [row][k], pad 136 -> conflict-free

  const int tid = threadIdx.x;
  for (int idx = tid; idx < 128 * 64; idx += 256){
    int k = idx >> 6, c = idx & 63;
    Wl[idx] = (c < wcols) ? W[(size_t)k * ldW + c] : 0.f;
  }

  // per-thread staging column group is invariant: c8 = tid & 15
  float sc8[8], sh8[8];
  if (BN){
    int c0 = (tid & 15) << 3;
    #pragma unroll
    for (int j = 0; j < 8; j++){ sc8[j] = scale[c0 + j]; sh8[j] = shift[c0 + j]; }
  }

  const int tc = tid & 7;          // col group 0..7 (8 cols each... 4+4 split)
  const int tr = tid >> 3;         // row group 0..31

  for (int t = blockIdx.x; t < ntiles; t += gridDim.x){
    const int r0 = t << 7;
    __syncthreads();
    // stage X tile (bf16 in LDS)
    for (int idx = tid; idx < 128 * 16; idx += 256){
      int row = idx >> 4, c8 = idx & 15;
      int gr = r0 + row;
      float x[8];
      if (gr < n){
        if (XBF){
          const u16* p = (const u16*)Xv + ((size_t)gr << 7) + (c8 << 3);
          uint4 u = *(const uint4*)p;
          x[0] = b2f((u16)u.x); x[1] = b2f((u16)(u.x >> 16));
          x[2] = b2f((u16)u.y); x[3] = b2f((u16)(u.y >> 16));
          x[4] = b2f((u16)u.z); x[5] = b2f((u16)(u.z >> 16));
          x[6] = b2f((u16)u.w); x[7] = b2f((u16)(u.w >> 16));
        } else {
          const float* p = (const float*)Xv + ((size_t)gr << 7) + (c8 << 3);
          float4 a = *(const float4*)p;
          float4 b = *(const float4*)(p + 4);
          x[0]=a.x; x[1]=a.y; x[2]=a.z; x[3]=a.w;
          x[4]=b.x; x[5]=b.y; x[6]=b.z; x[7]=b.w;
        }
        if (BN){
          #pragma unroll
          for (int j = 0; j < 8; j++)
            x[j] = fmaxf(fmaf(x[j], sc8[j], sh8[j]), 0.f);
        }
      } else {
        #pragma unroll
        for (int j = 0; j < 8; j++) x[j] = 0.f;
      }
      uint4 u;
      u.x = (u32)f2b(x[0]) | ((u32)f2b(x[1]) << 16);
      u.y = (u32)f2b(x[2]) | ((u32)f2b(x[3]) << 16);
      u.z = (u32)f2b(x[4]) | ((u32)f2b(x[5]) << 16);
      u.w = (u32)f2b(x[6]) | ((u32)f2b(x[7]) << 16);
      *(uint4*)(Xl + row * 136 + (c8 << 3)) = u;
    }
    __syncthreads();

    float4 acc[4][2];
    #pragma unroll
    for (int i = 0; i < 4; i++){ acc[i][0] = f4zero(); acc[i][1] = f4zero(); }

    for (int k8 = 0; k8 < 16; k8++){
      float xf[4][8];
      #pragma unroll
      for (int i = 0; i < 4; i++){
        uint4 u = *(const uint4*)(Xl + (tr + 32 * i) * 136 + (k8 << 3));
        xf[i][0] = b2f((u16)u.x); xf[i][1] = b2f((u16)(u.x >> 16));
        xf[i][2] = b2f((u16)u.y); xf[i][3] = b2f((u16)(u.y >> 16));
        xf[i][4] = b2f((u16)u.z); xf[i][5] = b2f((u16)(u.z >> 16));
        xf[i][6] = b2f((u16)u.w); xf[i][7] = b2f((u16)(u.w >> 16));
      }
      #pragma unroll
      for (int kk = 0; kk < 8; kk++){
        const float* wr = Wl + (((k8 << 3) + kk) << 6) + (tc << 2);
        float4 w0 = *(const float4*)wr;
        float4 w1 = *(const float4*)(wr + 32);
        #pragma unroll
        for (int i = 0; i < 4; i++){
          acc[i][0] = f4fma(xf[i][kk], w0, acc[i][0]);
          acc[i][1] = f4fma(xf[i][kk], w1, acc[i][1]);
        }
      }
    }

    #pragma unroll
    for (int i = 0; i < 4; i++){
      int row = r0 + tr + 32 * i;
      if (row < n){
        #pragma unroll
        for (int jq = 0; jq < 2; jq++){
          int cq = (tc << 2) + (jq << 5);
          if (cq < wcols){
            float4 a = acc[i][jq];
            ushort4 h;
            h.x = f2b(a.x); h.y = f2b(a.y); h.z = f2b(a.z); h.w = f2b(a.w);
            *(ushort4*)(Y + (size_t)row * ldY + col_off + cq) = h;
          }
        }
      }
    }
  }
}

// ---------- aggregation (CSR gather, bf16 rows): out = di*(sum_s h[s]*dinv[s] + di*h[n]) ----------
__global__ void k_agg128(const u16* __restrict__ H, u16* __restrict__ Y,
                         const int* __restrict__ rowstart, const int* __restrict__ cnt,
                         const int* __restrict__ csr, const float* __restrict__ dinv, int n){
  int t = blockIdx.x * blockDim.x + threadIdx.x;
  int node = t >> 4, c8 = t & 15;
  if (node >= n) return;
  float di = dinv[node];
  float acc[8];
  {
    uint4 u = *(const uint4*)(H + ((size_t)node << 7) + (c8 << 3));
    acc[0] = b2f((u16)u.x) * di; acc[1] = b2f((u16)(u.x >> 16)) * di;
    acc[2] = b2f((u16)u.y) * di; acc[3] = b2f((u16)(u.y >> 16)) * di;
    acc[4] = b2f((u16)u.z) * di; acc[5] = b2f((u16)(u.z >> 16)) * di;
    acc[6] = b2f((u16)u.w) * di; acc[7] = b2f((u16)(u.w >> 16)) * di;
  }
  int beg = rowstart[node], num = cnt[node];
  for (int i = 0; i < num; i++){
    int s = csr[beg + i];
    float w = dinv[s];
    uint4 u = *(const uint4*)(H + ((size_t)s << 7) + (c8 << 3));
    acc[0] = fmaf(b2f((u16)u.x),         w, acc[0]);
    acc[1] = fmaf(b2f((u16)(u.x >> 16)), w, acc[1]);
    acc[2] = fmaf(b2f((u16)u.y),         w, acc[2]);
    acc[3] = fmaf(b2f((u16)(u.y >> 16)), w, acc[3]);
    acc[4] = fmaf(b2f((u16)u.z),         w, acc[4]);
    acc[5] = fmaf(b2f((u16)(u.z >> 16)), w, acc[5]);
    acc[6] = fmaf(b2f((u16)u.w),         w, acc[6]);
    acc[7] = fmaf(b2f((u16)(u.w >> 16)), w, acc[7]);
  }
  uint4 o;
  o.x = (u32)f2b(acc[0] * di) | ((u32)f2b(acc[1] * di) << 16);
  o.y = (u32)f2b(acc[2] * di) | ((u32)f2b(acc[3] * di) << 16);
  o.z = (u32)f2b(acc[4] * di) | ((u32)f2b(acc[5] * di) << 16);
  o.w = (u32)f2b(acc[6] * di) | ((u32)f2b(acc[7] * di) << 16);
  *(uint4*)(Y + ((size_t)node << 7) + (c8 << 3)) = o;
}

// H: compact bf16 [n][40]; output fp32 [n][40] with b_out added
__global__ void k_agg40(const u16* __restrict__ H, const float* __restrict__ bout,
                        float* __restrict__ Y, const int* __restrict__ rowstart,
                        const int* __restrict__ cnt, const int* __restrict__ csr,
                        const float* __restrict__ dinv, int n){
  int t = blockIdx.x * blockDim.x + threadIdx.x;
  int node = t >> 4, c4 = t & 15;
  if (node >= n || c4 >= 10) return;
  float di = dinv[node];
  float acc[4];
  {
    uint2 u = *(const uint2*)(H + (size_t)node * NOUT + (c4 << 2));
    acc[0] = b2f((u16)u.x) * di; acc[1] = b2f((u16)(u.x >> 16)) * di;
    acc[2] = b2f((u16)u.y) * di; acc[3] = b2f((u16)(u.y >> 16)) * di;
  }
  int beg = rowstart[node], num = cnt[node];
  for (int i = 0; i < num; i++){
    int s = csr[beg + i];
    float w = dinv[s];
    uint2 u = *(const uint2*)(H + (size_t)s * NOUT + (c4 << 2));
    acc[0] = fmaf(b2f((u16)u.x),         w, acc[0]);
    acc[1] = fmaf(b2f((u16)(u.x >> 16)), w, acc[1]);
    acc[2] = fmaf(b2f((u16)u.y),         w, acc[2]);
    acc[3] = fmaf(b2f((u16)(u.y >> 16)), w, acc[3]);
  }
  float4 bb = *(const float4*)(bout + (c4 << 2));
  float4 o;
  o.x = fmaf(acc[0], di, bb.x); o.y = fmaf(acc[1], di, bb.y);
  o.z = fmaf(acc[2], di, bb.z); o.w = fmaf(acc[3], di, bb.w);
  *(float4*)(Y + (size_t)node * NOUT + (c4 << 2)) = o;
}

// ---------- BatchNorm stats (bf16 input) ----------
__global__ void k_bn_stats(const u16* __restrict__ X, float* __restrict__ sum,
                           float* __restrict__ sq, int n){
  int c = threadIdx.x & 127, half = threadIdx.x >> 7;
  float s = 0.f, q = 0.f;
  for (int r = blockIdx.x * 2 + half; r < n; r += gridDim.x * 2){
    float v = b2f(X[((size_t)r << 7) + c]);
    s += v; q = fmaf(v, v, q);
  }
  __shared__ float ls[256], lq[256];
  ls[threadIdx.x] = s; lq[threadIdx.x] = q;
  __syncthreads();
  if (threadIdx.x < 128){
    s = ls[threadIdx.x] + ls[threadIdx.x + 128];
    q = lq[threadIdx.x] + lq[threadIdx.x + 128];
    atomicAdd(&sum[c], s); atomicAdd(&sq[c], q);
  }
}

__global__ void k_bn_fin(const float* __restrict__ sum, const float* __restrict__ sq,
                         const float* __restrict__ g, const float* __restrict__ beta,
                         float* __restrict__ scale, float* __restrict__ shift, int n){
  int c = threadIdx.x;
  if (c < 128){
    float invn = 1.0f / (float)n;
    float mu  = sum[c] * invn;
    float var = sq[c] * invn - mu * mu;
    var = var > 0.f ? var : 0.f;
    float sc = g[c] * rsqrtf(var + BN_EPS);
    scale[c] = sc;
    shift[c] = beta[c] - mu * sc;
  }
}

// ---------- launch ----------
extern "C" void kernel_launch(void* const* d_in, const int* in_sizes, int n_in,
                              void* d_out, int out_size, void* d_ws, size_t ws_size,
                              hipStream_t stream) {
  const float* x0        = (const float*)d_in[0];
  const float* x1        = (const float*)d_in[1];
  const int*   ei        = (const int*)  d_in[2];
  const float* W_init    = (const float*)d_in[3];
  const float* g_init    = (const float*)d_in[5];
  const float* beta_init = (const float*)d_in[6];
  const float* W_mid     = (const float*)d_in[7];
  const float* g_mid     = (const float*)d_in[9];
  const float* beta_mid  = (const float*)d_in[10];
  const float* W_out     = (const float*)d_in[11];
  const float* b_out     = (const float*)d_in[12];

  int N = in_sizes[0] / F_IN;
  int E = in_sizes[2] / 2;
  const int* esrc = ei;
  const int* edst = ei + E;

  char* w = (char*)d_ws;
  size_t off = 0;
  auto take = [&](size_t bytes) -> char* {
    char* p = w + off;
    off = (off + bytes + 255) & ~(size_t)255;
    return p;
  };
  float* dinv     = (float*)take((size_t)N * 4);
  int*   cnt      = (int*)  take((size_t)N * 4);
  int*   fill     = (int*)  take((size_t)N * 4);
  int*   rowstart = (int*)  take((size_t)N * 4);
  int NB = ceil_div_l(N, 256);
  int*   bsum     = (int*)  take((size_t)NB * 4);
  int*   boff     = (int*)  take((size_t)NB * 4);
  float* stats    = (float*)take(1024 * 4);
  int*   csr      = (int*)  take((size_t)E * 4);
  u16*   A        = (u16*)  take((size_t)N * 128 * 2);
  u16*   B        = (u16*)  take((size_t)N * 128 * 2);
  (void)ws_size; (void)n_in; (void)out_size;

  float* sum1 = stats,       *sq1 = stats + 128, *scale1 = stats + 256, *shift1 = stats + 384;
  float* sum2 = stats + 512, *sq2 = stats + 640, *scale2 = stats + 768, *shift2 = stats + 896;

  hipMemsetAsync(cnt,   0, (size_t)N * 4, stream);
  hipMemsetAsync(fill,  0, (size_t)N * 4, stream);
  hipMemsetAsync(stats, 0, 1024 * 4, stream);

  // norm + CSR
  k_count<<<ceil_div_l(E,256),256,0,stream>>>(edst, cnt, E);
  k_dinv <<<ceil_div_l(N,256),256,0,stream>>>(cnt, dinv, N);
  k_block_reduce<<<NB,256,0,stream>>>(cnt, bsum, N);
  k_top_scan   <<<1,64,0,stream>>>(bsum, boff, NB);
  k_local_scan <<<NB,256,0,stream>>>(cnt, boff, rowstart, N);
  k_place<<<ceil_div_l(E,256),256,0,stream>>>(esrc, edst, rowstart, fill, csr, E);

  const int ntiles = ceil_div_l(N, 128);
  const int GB = 512;  // 2 blocks/CU

  // layer 1: two branch GEMMs (fp32 X, no BN) into concat bf16 A
  k_gemm64<false,false><<<GB,256,0,stream>>>(x0, W_init,           64, 64, nullptr, nullptr, A, 128,  0, N, ntiles);
  k_gemm64<false,false><<<GB,256,0,stream>>>(x1, W_init + 128*64,  64, 64, nullptr, nullptr, A, 128, 64, N, ntiles);
  k_agg128<<<ceil_div_l((long)N*16,256),256,0,stream>>>(A, B, rowstart, cnt, csr, dinv, N);
  k_bn_stats<<<512,256,0,stream>>>(B, sum1, sq1, N);
  k_bn_fin<<<1,128,0,stream>>>(sum1, sq1, g_init, beta_init, scale1, shift1, N);

  // layer 2: BN1+ReLU fused into staging; two 64-col halves of W_mid
  k_gemm64<true,true><<<GB,256,0,stream>>>(B, W_mid,      128, 64, scale1, shift1, A, 128,  0, N, ntiles);
  k_gemm64<true,true><<<GB,256,0,stream>>>(B, W_mid + 64, 128, 64, scale1, shift1, A, 128, 64, N, ntiles);
  k_agg128<<<ceil_div_l((long)N*16,256),256,0,stream>>>(A, B, rowstart, cnt, csr, dinv, N);
  k_bn_stats<<<512,256,0,stream>>>(B, sum2, sq2, N);
  k_bn_fin<<<1,128,0,stream>>>(sum2, sq2, g_mid, beta_mid, scale2, shift2, N);

  // layer 3: BN2+ReLU fused; 40 cols (pad to 64 in compute), compact bf16 out
  k_gemm64<true,true><<<GB,256,0,stream>>>(B, W_out, 40, 40, scale2, shift2, A, 40, 0, N, ntiles);
  k_agg40<<<ceil_div_l((long)N*16,256),256,0,stream>>>(A, b_out, (float*)d_out,
                                                       rowstart, cnt, csr, dinv, N);
}

// Round 4
// 569.741 us; speedup vs baseline: 2.3001x; 1.2478x over previous
//
#include <hip/hip_runtime.h>
#include <cstdint>
#include <cstddef>

#define F_IN 128
#define NOUT 40
#define BN_EPS 1e-5f
#define RBITS 8
#define RSIZE 256           // nodes per range
#define MAXNR 512           // supports N <= 131072

typedef unsigned short u16;
typedef unsigned int u32;

static inline int ceil_div_l(long a, long b){ return (int)((a + b - 1) / b); }

__device__ __forceinline__ float4 f4zero(){ return make_float4(0.f,0.f,0.f,0.f); }
__device__ __forceinline__ float4 f4fma(float a, float4 b, float4 c){
  c.x = fmaf(a, b.x, c.x); c.y = fmaf(a, b.y, c.y);
  c.z = fmaf(a, b.z, c.z); c.w = fmaf(a, b.w, c.w); return c;
}
__device__ __forceinline__ float b2f(u16 h){
  union { u32 u; float f; } v; v.u = ((u32)h) << 16; return v.f;
}
__device__ __forceinline__ u16 f2b(float x){
  union { float f; u32 u; } v; v.f = x;
  u32 r = v.u + 0x7FFFu + ((v.u >> 16) & 1u);
  return (u16)(r >> 16);
}

// ---------- A1: per-range edge counts (LDS histogram, few global atomics) ----------
__global__ void k_rangecount(const int* __restrict__ dst, int* __restrict__ rangecnt,
                             int E, int NR, int chunk){
  __shared__ u32 hist[MAXNR];
  for (int i = threadIdx.x; i < NR; i += 256) hist[i] = 0;
  __syncthreads();
  int s = blockIdx.x * chunk;
  int e_end = min(s + chunk, E);
  for (int e = s + threadIdx.x; e < e_end; e += 256)
    atomicAdd(&hist[(u32)dst[e] >> RBITS], 1u);
  __syncthreads();
  for (int i = threadIdx.x; i < NR; i += 256){
    u32 h = hist[i];
    if (h) atomicAdd((u32*)&rangecnt[i], h);
  }
}

// ---------- A2: exclusive scan of range counts ----------
__global__ void k_rangescan(const int* __restrict__ rangecnt, int* __restrict__ rangebase,
                            int NR){
  __shared__ int s[MAXNR];
  int t = threadIdx.x;
  if (t < NR) s[t] = rangecnt[t];
  __syncthreads();
  if (t == 0){
    int acc = 0;
    for (int i = 0; i < NR; i++){ int v = s[i]; s[i] = acc; acc += v; }
  }
  __syncthreads();
  if (t < NR) rangebase[t] = s[t];
}

// ---------- A3: partition edges into per-range segments (packed u32) ----------
__global__ void k_partition(const int* __restrict__ src, const int* __restrict__ dst,
                            const int* __restrict__ rangebase, int* __restrict__ rangefill,
                            u32* __restrict__ part, int E, int NR, int chunk){
  __shared__ u32 hist[MAXNR];
  __shared__ u32 lbase[MAXNR];
  for (int i = threadIdx.x; i < NR; i += 256) hist[i] = 0;
  __syncthreads();
  int s0 = blockIdx.x * chunk;
  int e_end = min(s0 + chunk, E);
  for (int e = s0 + threadIdx.x; e < e_end; e += 256)
    atomicAdd(&hist[(u32)dst[e] >> RBITS], 1u);
  __syncthreads();
  for (int i = threadIdx.x; i < NR; i += 256){
    u32 h = hist[i];
    u32 b = h ? (u32)atomicAdd((u32*)&rangefill[i], h) : 0u;
    lbase[i] = (u32)rangebase[i] + b;
    hist[i] = 0;                       // reuse as local fill
  }
  __syncthreads();
  for (int e = s0 + threadIdx.x; e < e_end; e += 256){
    u32 d = (u32)dst[e];
    u32 r = d >> RBITS;
    u32 pos = lbase[r] + atomicAdd(&hist[r], 1u);
    part[pos] = (u32)src[e] | ((d & (RSIZE - 1)) << 17);
  }
}

// ---------- B: per-range CSR build + dinv (all LDS atomics) ----------
__global__ void k_build(const u32* __restrict__ part, const int* __restrict__ rangecnt,
                        const int* __restrict__ rangebase, int* __restrict__ rowstart,
                        int* __restrict__ cnt, float* __restrict__ dinv,
                        int* __restrict__ csr, int n){
  __shared__ int hist[RSIZE];
  __shared__ int scanx[RSIZE];
  __shared__ int fill[RSIZE];
  int r = blockIdx.x;
  int ne = rangecnt[r], base = rangebase[r];
  int t = threadIdx.x;
  hist[t] = 0;
  __syncthreads();
  for (int i = t; i < ne; i += 256) atomicAdd(&hist[part[base + i] >> 17], 1);
  __syncthreads();
  int v = hist[t];
  scanx[t] = v;
  __syncthreads();
  for (int o = 1; o < 256; o <<= 1){
    int tv = (t >= o) ? scanx[t - o] : 0;
    __syncthreads();
    scanx[t] += tv;
    __syncthreads();
  }
  int excl = scanx[t] - v;
  int node = (r << RBITS) + t;
  if (node < n){
    rowstart[node] = base + excl;
    cnt[node]      = v;
    dinv[node]     = rsqrtf(1.0f + (float)v);
  }
  fill[t] = 0;
  scanx[t] = excl;
  __syncthreads();
  for (int i = t; i < ne; i += 256){
    u32 p = part[base + i];
    int dl = (int)(p >> 17);
    int pos = scanx[dl] + atomicAdd(&fill[dl], 1);
    csr[base + pos] = (int)(p & 0x1FFFFu);
  }
}

// ---------- register-tiled GEMM, 128-row x 64-col tile, bf16 out ----------
template<bool XBF, bool BN>
__launch_bounds__(256, 2)
__global__ void k_gemm64(const void* __restrict__ Xv, const float* __restrict__ W,
                         int ldW, int wcols,
                         const float* __restrict__ scale, const float* __restrict__ shift,
                         u16* __restrict__ Y, int ldY, int col_off, int n, int ntiles){
  __shared__ float Wl[128 * 64];      // [k][c]
  __shared__ u16   Xl[128 * 136];     // [row][k], pad 136 -> conflict-free

  const int tid = threadIdx.x;
  for (int idx = tid; idx < 128 * 64; idx += 256){
    int k = idx >> 6, c = idx & 63;
    Wl[idx] = (c < wcols) ? W[(size_t)k * ldW + c] : 0.f;
  }

  float sc8[8], sh8[8];
  if (BN){
    int c0 = (tid & 15) << 3;
    #pragma unroll
    for (int j = 0; j < 8; j++){ sc8[j] = scale[c0 + j]; sh8[j] = shift[c0 + j]; }
  }

  const int tc = tid & 7;
  const int tr = tid >> 3;

  for (int t = blockIdx.x; t < ntiles; t += gridDim.x){
    const int r0 = t << 7;
    __syncthreads();
    for (int idx = tid; idx < 128 * 16; idx += 256){
      int row = idx >> 4, c8 = idx & 15;
      int gr = r0 + row;
      float x[8];
      if (gr < n){
        if (XBF){
          const u16* p = (const u16*)Xv + ((size_t)gr << 7) + (c8 << 3);
          uint4 u = *(const uint4*)p;
          x[0] = b2f((u16)u.x); x[1] = b2f((u16)(u.x >> 16));
          x[2] = b2f((u16)u.y); x[3] = b2f((u16)(u.y >> 16));
          x[4] = b2f((u16)u.z); x[5] = b2f((u16)(u.z >> 16));
          x[6] = b2f((u16)u.w); x[7] = b2f((u16)(u.w >> 16));
        } else {
          const float* p = (const float*)Xv + ((size_t)gr << 7) + (c8 << 3);
          float4 a = *(const float4*)p;
          float4 b = *(const float4*)(p + 4);
          x[0]=a.x; x[1]=a.y; x[2]=a.z; x[3]=a.w;
          x[4]=b.x; x[5]=b.y; x[6]=b.z; x[7]=b.w;
        }
        if (BN){
          #pragma unroll
          for (int j = 0; j < 8; j++)
            x[j] = fmaxf(fmaf(x[j], sc8[j], sh8[j]), 0.f);
        }
      } else {
        #pragma unroll
        for (int j = 0; j < 8; j++) x[j] = 0.f;
      }
      uint4 u;
      u.x = (u32)f2b(x[0]) | ((u32)f2b(x[1]) << 16);
      u.y = (u32)f2b(x[2]) | ((u32)f2b(x[3]) << 16);
      u.z = (u32)f2b(x[4]) | ((u32)f2b(x[5]) << 16);
      u.w = (u32)f2b(x[6]) | ((u32)f2b(x[7]) << 16);
      *(uint4*)(Xl + row * 136 + (c8 << 3)) = u;
    }
    __syncthreads();

    float4 acc[4][2];
    #pragma unroll
    for (int i = 0; i < 4; i++){ acc[i][0] = f4zero(); acc[i][1] = f4zero(); }

    for (int k8 = 0; k8 < 16; k8++){
      float xf[4][8];
      #pragma unroll
      for (int i = 0; i < 4; i++){
        uint4 u = *(const uint4*)(Xl + (tr + 32 * i) * 136 + (k8 << 3));
        xf[i][0] = b2f((u16)u.x); xf[i][1] = b2f((u16)(u.x >> 16));
        xf[i][2] = b2f((u16)u.y); xf[i][3] = b2f((u16)(u.y >> 16));
        xf[i][4] = b2f((u16)u.z); xf[i][5] = b2f((u16)(u.z >> 16));
        xf[i][6] = b2f((u16)u.w); xf[i][7] = b2f((u16)(u.w >> 16));
      }
      #pragma unroll
      for (int kk = 0; kk < 8; kk++){
        const float* wr = Wl + (((k8 << 3) + kk) << 6) + (tc << 2);
        float4 w0 = *(const float4*)wr;
        float4 w1 = *(const float4*)(wr + 32);
        #pragma unroll
        for (int i = 0; i < 4; i++){
          acc[i][0] = f4fma(xf[i][kk], w0, acc[i][0]);
          acc[i][1] = f4fma(xf[i][kk], w1, acc[i][1]);
        }
      }
    }

    #pragma unroll
    for (int i = 0; i < 4; i++){
      int row = r0 + tr + 32 * i;
      if (row < n){
        #pragma unroll
        for (int jq = 0; jq < 2; jq++){
          int cq = (tc << 2) + (jq << 5);
          if (cq < wcols){
            float4 a = acc[i][jq];
            ushort4 h;
            h.x = f2b(a.x); h.y = f2b(a.y); h.z = f2b(a.z); h.w = f2b(a.w);
            *(ushort4*)(Y + (size_t)row * ldY + col_off + cq) = h;
          }
        }
      }
    }
  }
}

// ---------- aggregation (CSR gather, bf16 rows) ----------
__global__ void k_agg128(const u16* __restrict__ H, u16* __restrict__ Y,
                         const int* __restrict__ rowstart, const int* __restrict__ cnt,
                         const int* __restrict__ csr, const float* __restrict__ dinv, int n){
  int t = blockIdx.x * blockDim.x + threadIdx.x;
  int node = t >> 4, c8 = t & 15;
  if (node >= n) return;
  float di = dinv[node];
  float acc[8];
  {
    uint4 u = *(const uint4*)(H + ((size_t)node << 7) + (c8 << 3));
    acc[0] = b2f((u16)u.x) * di; acc[1] = b2f((u16)(u.x >> 16)) * di;
    acc[2] = b2f((u16)u.y) * di; acc[3] = b2f((u16)(u.y >> 16)) * di;
    acc[4] = b2f((u16)u.z) * di; acc[5] = b2f((u16)(u.z >> 16)) * di;
    acc[6] = b2f((u16)u.w) * di; acc[7] = b2f((u16)(u.w >> 16)) * di;
  }
  int beg = rowstart[node], num = cnt[node];
  for (int i = 0; i < num; i++){
    int s = csr[beg + i];
    float w = dinv[s];
    uint4 u = *(const uint4*)(H + ((size_t)s << 7) + (c8 << 3));
    acc[0] = fmaf(b2f((u16)u.x),         w, acc[0]);
    acc[1] = fmaf(b2f((u16)(u.x >> 16)), w, acc[1]);
    acc[2] = fmaf(b2f((u16)u.y),         w, acc[2]);
    acc[3] = fmaf(b2f((u16)(u.y >> 16)), w, acc[3]);
    acc[4] = fmaf(b2f((u16)u.z),         w, acc[4]);
    acc[5] = fmaf(b2f((u16)(u.z >> 16)), w, acc[5]);
    acc[6] = fmaf(b2f((u16)u.w),         w, acc[6]);
    acc[7] = fmaf(b2f((u16)(u.w >> 16)), w, acc[7]);
  }
  uint4 o;
  o.x = (u32)f2b(acc[0] * di) | ((u32)f2b(acc[1] * di) << 16);
  o.y = (u32)f2b(acc[2] * di) | ((u32)f2b(acc[3] * di) << 16);
  o.z = (u32)f2b(acc[4] * di) | ((u32)f2b(acc[5] * di) << 16);
  o.w = (u32)f2b(acc[6] * di) | ((u32)f2b(acc[7] * di) << 16);
  *(uint4*)(Y + ((size_t)node << 7) + (c8 << 3)) = o;
}

__global__ void k_agg40(const u16* __restrict__ H, const float* __restrict__ bout,
                        float* __restrict__ Y, const int* __restrict__ rowstart,
                        const int* __restrict__ cnt, const int* __restrict__ csr,
                        const float* __restrict__ dinv, int n){
  int t = blockIdx.x * blockDim.x + threadIdx.x;
  int node = t >> 4, c4 = t & 15;
  if (node >= n || c4 >= 10) return;
  float di = dinv[node];
  float acc[4];
  {
    uint2 u = *(const uint2*)(H + (size_t)node * NOUT + (c4 << 2));
    acc[0] = b2f((u16)u.x) * di; acc[1] = b2f((u16)(u.x >> 16)) * di;
    acc[2] = b2f((u16)u.y) * di; acc[3] = b2f((u16)(u.y >> 16)) * di;
  }
  int beg = rowstart[node], num = cnt[node];
  for (int i = 0; i < num; i++){
    int s = csr[beg + i];
    float w = dinv[s];
    uint2 u = *(const uint2*)(H + (size_t)s * NOUT + (c4 << 2));
    acc[0] = fmaf(b2f((u16)u.x),         w, acc[0]);
    acc[1] = fmaf(b2f((u16)(u.x >> 16)), w, acc[1]);
    acc[2] = fmaf(b2f((u16)u.y),         w, acc[2]);
    acc[3] = fmaf(b2f((u16)(u.y >> 16)), w, acc[3]);
  }
  float4 bb = *(const float4*)(bout + (c4 << 2));
  float4 o;
  o.x = fmaf(acc[0], di, bb.x); o.y = fmaf(acc[1], di, bb.y);
  o.z = fmaf(acc[2], di, bb.z); o.w = fmaf(acc[3], di, bb.w);
  *(float4*)(Y + (size_t)node * NOUT + (c4 << 2)) = o;
}

// ---------- BatchNorm stats (bf16 input) ----------
__global__ void k_bn_stats(const u16* __restrict__ X, float* __restrict__ sum,
                           float* __restrict__ sq, int n){
  int c = threadIdx.x & 127, half = threadIdx.x >> 7;
  float s = 0.f, q = 0.f;
  for (int r = blockIdx.x * 2 + half; r < n; r += gridDim.x * 2){
    float v = b2f(X[((size_t)r << 7) + c]);
    s += v; q = fmaf(v, v, q);
  }
  __shared__ float ls[256], lq[256];
  ls[threadIdx.x] = s; lq[threadIdx.x] = q;
  __syncthreads();
  if (threadIdx.x < 128){
    s = ls[threadIdx.x] + ls[threadIdx.x + 128];
    q = lq[threadIdx.x] + lq[threadIdx.x + 128];
    atomicAdd(&sum[c], s); atomicAdd(&sq[c], q);
  }
}

__global__ void k_bn_fin(const float* __restrict__ sum, const float* __restrict__ sq,
                         const float* __restrict__ g, const float* __restrict__ beta,
                         float* __restrict__ scale, float* __restrict__ shift, int n){
  int c = threadIdx.x;
  if (c < 128){
    float invn = 1.0f / (float)n;
    float mu  = sum[c] * invn;
    float var = sq[c] * invn - mu * mu;
    var = var > 0.f ? var : 0.f;
    float sc = g[c] * rsqrtf(var + BN_EPS);
    scale[c] = sc;
    shift[c] = beta[c] - mu * sc;
  }
}

// ---------- launch ----------
extern "C" void kernel_launch(void* const* d_in, const int* in_sizes, int n_in,
                              void* d_out, int out_size, void* d_ws, size_t ws_size,
                              hipStream_t stream) {
  const float* x0        = (const float*)d_in[0];
  const float* x1        = (const float*)d_in[1];
  const int*   ei        = (const int*)  d_in[2];
  const float* W_init    = (const float*)d_in[3];
  const float* g_init    = (const float*)d_in[5];
  const float* beta_init = (const float*)d_in[6];
  const float* W_mid     = (const float*)d_in[7];
  const float* g_mid     = (const float*)d_in[9];
  const float* beta_mid  = (const float*)d_in[10];
  const float* W_out     = (const float*)d_in[11];
  const float* b_out     = (const float*)d_in[12];

  int N = in_sizes[0] / F_IN;
  int E = in_sizes[2] / 2;
  const int* esrc = ei;
  const int* edst = ei + E;
  int NR = (N + RSIZE - 1) >> RBITS;

  char* w = (char*)d_ws;
  size_t off = 0;
  auto take = [&](size_t bytes) -> char* {
    char* p = w + off;
    off = (off + bytes + 255) & ~(size_t)255;
    return p;
  };
  float* dinv      = (float*)take((size_t)N * 4);
  int*   cnt       = (int*)  take((size_t)N * 4);
  int*   rowstart  = (int*)  take((size_t)N * 4);
  int*   rangecnt  = (int*)  take((size_t)MAXNR * 4);
  int*   rangebase = (int*)  take((size_t)MAXNR * 4);
  int*   rangefill = (int*)  take((size_t)MAXNR * 4);
  float* stats     = (float*)take(1024 * 4);
  u32*   part      = (u32*)  take((size_t)E * 4);
  int*   csr       = (int*)  take((size_t)E * 4);
  u16*   A         = (u16*)  take((size_t)N * 128 * 2);
  u16*   B         = (u16*)  take((size_t)N * 128 * 2);
  (void)ws_size; (void)n_in; (void)out_size;

  float* sum1 = stats,       *sq1 = stats + 128, *scale1 = stats + 256, *shift1 = stats + 384;
  float* sum2 = stats + 512, *sq2 = stats + 640, *scale2 = stats + 768, *shift2 = stats + 896;

  hipMemsetAsync(rangecnt,  0, (size_t)MAXNR * 4, stream);
  hipMemsetAsync(rangefill, 0, (size_t)MAXNR * 4, stream);
  hipMemsetAsync(stats,     0, 1024 * 4, stream);

  // CSR build via range partition (no global per-edge atomics)
  const int PB = 512;
  const int chunk = ceil_div_l(E, PB);
  k_rangecount<<<PB, 256, 0, stream>>>(edst, rangecnt, E, NR, chunk);
  k_rangescan <<<1, MAXNR, 0, stream>>>(rangecnt, rangebase, NR);
  k_partition <<<PB, 256, 0, stream>>>(esrc, edst, rangebase, rangefill, part, E, NR, chunk);
  k_build     <<<NR, RSIZE, 0, stream>>>(part, rangecnt, rangebase, rowstart, cnt, dinv, csr, N);

  const int ntiles = ceil_div_l(N, 128);
  const int GB = 512;  // 2 blocks/CU

  // layer 1
  k_gemm64<false,false><<<GB,256,0,stream>>>(x0, W_init,           64, 64, nullptr, nullptr, A, 128,  0, N, ntiles);
  k_gemm64<false,false><<<GB,256,0,stream>>>(x1, W_init + 128*64,  64, 64, nullptr, nullptr, A, 128, 64, N, ntiles);
  k_agg128<<<ceil_div_l((long)N*16,256),256,0,stream>>>(A, B, rowstart, cnt, csr, dinv, N);
  k_bn_stats<<<512,256,0,stream>>>(B, sum1, sq1, N);
  k_bn_fin<<<1,128,0,stream>>>(sum1, sq1, g_init, beta_init, scale1, shift1, N);

  // layer 2
  k_gemm64<true,true><<<GB,256,0,stream>>>(B, W_mid,      128, 64, scale1, shift1, A, 128,  0, N, ntiles);
  k_gemm64<true,true><<<GB,256,0,stream>>>(B, W_mid + 64, 128, 64, scale1, shift1, A, 128, 64, N, ntiles);
  k_agg128<<<ceil_div_l((long)N*16,256),256,0,stream>>>(A, B, rowstart, cnt, csr, dinv, N);
  k_bn_stats<<<512,256,0,stream>>>(B, sum2, sq2, N);
  k_bn_fin<<<1,128,0,stream>>>(sum2, sq2, g_mid, beta_mid, scale2, shift2, N);

  // layer 3
  k_gemm64<true,true><<<GB,256,0,stream>>>(B, W_out, 40, 40, scale2, shift2, A, 40, 0, N, ntiles);
  k_agg40<<<ceil_div_l((long)N*16,256),256,0,stream>>>(A, b_out, (float*)d_out,
                                                       rowstart, cnt, csr, dinv, N);
}